// Round 2
// baseline (2013.391 us; speedup 1.0000x reference)
//
#include <hip/hip_runtime.h>
#include <cstdint>
#include <cstddef>

#define BB 32
#define LL 2048
#define DD 64
#define NKB 16   // k-blocks per row in k_scores (LL/128)

// masked scores get a huge negative finite value: expf(s - m) == 0 exactly,
// identical post-softmax to the reference's -inf / -1e32 fills.
#define BIG_NEG (-3.0e38f)

// ---------------------------------------------------------------------------
// K1: raw masked scores  S[b][q][k] = (q·k)/8, masked -> BIG_NEG
// tile 128(q) x 128(k), 256 threads, 8x8 micro, D chunked by 32 in LDS.
// Rotation swizzle col' = col + 4*(d>>2), stride 156: staging scatter and all
// fragment reads are 2-way (free).
// Mask/diag epilogue loads are software-pipelined (depth 2), with the first
// two row-groups issued before the last compute chunk so their ~900-cycle
// latency drains under FMA work.
// Emits per-(row, k-block) partial softmax stats pm/pl.
// ---------------------------------------------------------------------------
__global__ __launch_bounds__(256, 3) void k_scores(
    const float* __restrict__ q, const float* __restrict__ kmat,
    const int* __restrict__ diag, const int* __restrict__ mask,
    float* __restrict__ attn, float* __restrict__ pm, float* __restrict__ pl)
{
    __shared__ __align__(16) float sQT[32][156];  // [d][col'], col' <= 155
    __shared__ __align__(16) float sKT[32][156];

    const int b  = blockIdx.z;
    const int q0 = blockIdx.y * 128;
    const int k0 = blockIdx.x * 128;
    const int t  = threadIdx.x;
    const int tx = t & 15;
    const int ty = t >> 4;
    const int tyb = ty * 8;
    const int txb = tx * 4;

    const float* qb = q    + ((size_t)b * LL + q0) * DD;
    const float* kb = kmat + ((size_t)b * LL + k0) * DD;

    float acc[8][8];
    #pragma unroll
    for (int i = 0; i < 8; ++i)
        #pragma unroll
        for (int j = 0; j < 8; ++j) acc[i][j] = 0.0f;

    // mask/diag pipeline registers: [ri] slots, fully unrolled access only
    int4 dm0v[8], dm1v[8], mk0v[8], mk1v[8];

    #pragma unroll
    for (int dc = 0; dc < DD; dc += 32) {
        // stage 128 rows x 32 d of Q and K, transposed + rotation-swizzled
        #pragma unroll
        for (int i = 0; i < 4; ++i) {
            int lin = t + 256 * i;
            int row = lin >> 3;           // 0..127
            int dv  = lin & 7;            // d4 block 0..7
            int cc  = row + dv * 4;       // rotation swizzle
            float4 a = *(const float4*)(qb + (size_t)row * DD + dc + dv * 4);
            sQT[dv * 4 + 0][cc] = a.x;
            sQT[dv * 4 + 1][cc] = a.y;
            sQT[dv * 4 + 2][cc] = a.z;
            sQT[dv * 4 + 3][cc] = a.w;
            float4 c4 = *(const float4*)(kb + (size_t)row * DD + dc + dv * 4);
            sKT[dv * 4 + 0][cc] = c4.x;
            sKT[dv * 4 + 1][cc] = c4.y;
            sKT[dv * 4 + 2][cc] = c4.z;
            sKT[dv * 4 + 3][cc] = c4.w;
        }
        __syncthreads();

        // before the LAST compute chunk, issue mask loads for ri = 0,1:
        // they complete under ~4000 cycles of FMA below.
        if (dc == 32) {
            #pragma unroll
            for (int r = 0; r < 2; ++r) {
                int qq = q0 + tyb + r;
                size_t base = ((size_t)b * LL + qq) * LL + k0 + txb;
                dm0v[r] = *(const int4*)(diag + base);
                dm1v[r] = *(const int4*)(diag + base + 64);
                mk0v[r] = *(const int4*)(mask + base);
                mk1v[r] = *(const int4*)(mask + base + 64);
            }
        }

        #pragma unroll
        for (int d = 0; d < 32; ++d) {
            const int rot = d & 28;
            float4 a0 = *(const float4*)&sQT[d][tyb + rot];
            float4 a1 = *(const float4*)&sQT[d][tyb + 4 + rot];
            float4 b0 = *(const float4*)&sKT[d][txb + rot];
            float4 b1 = *(const float4*)&sKT[d][txb + 64 + rot];
            float aa[8] = {a0.x, a0.y, a0.z, a0.w, a1.x, a1.y, a1.z, a1.w};
            float bb[8] = {b0.x, b0.y, b0.z, b0.w, b1.x, b1.y, b1.z, b1.w};
            #pragma unroll
            for (int ri = 0; ri < 8; ++ri)
                #pragma unroll
                for (int ci = 0; ci < 8; ++ci)
                    acc[ri][ci] = fmaf(aa[ri], bb[ci], acc[ri][ci]);
        }
        __syncthreads();
    }

    // epilogue, software-pipelined depth 2
    #pragma unroll
    for (int ri = 0; ri < 8; ++ri) {
        int qq = q0 + tyb + ri;
        size_t rb    = ((size_t)b * LL + qq) * LL + k0;
        size_t base0 = rb + txb;
        size_t base1 = rb + txb + 64;

        if (ri < 6) {   // issue loads for slot ri+2 ahead of use
            int qq2 = q0 + tyb + ri + 2;
            size_t b2 = ((size_t)b * LL + qq2) * LL + k0 + txb;
            dm0v[ri + 2] = *(const int4*)(diag + b2);
            dm1v[ri + 2] = *(const int4*)(diag + b2 + 64);
            mk0v[ri + 2] = *(const int4*)(mask + b2);
            mk1v[ri + 2] = *(const int4*)(mask + b2 + 64);
        }

        int dmv[8] = {dm0v[ri].x, dm0v[ri].y, dm0v[ri].z, dm0v[ri].w,
                      dm1v[ri].x, dm1v[ri].y, dm1v[ri].z, dm1v[ri].w};
        int mkv[8] = {mk0v[ri].x, mk0v[ri].y, mk0v[ri].z, mk0v[ri].w,
                      mk1v[ri].x, mk1v[ri].y, mk1v[ri].z, mk1v[ri].w};
        float o[8];
        #pragma unroll
        for (int ci = 0; ci < 8; ++ci) {
            float s = acc[ri][ci] * 0.125f;
            o[ci] = (dmv[ci] == 0 || mkv[ci] != 0) ? BIG_NEG : s;
        }
        *(float4*)(attn + base0) = make_float4(o[0], o[1], o[2], o[3]);
        *(float4*)(attn + base1) = make_float4(o[4], o[5], o[6], o[7]);

        if (pm != nullptr) {
            float rm = fmaxf(fmaxf(fmaxf(o[0], o[1]), fmaxf(o[2], o[3])),
                             fmaxf(fmaxf(o[4], o[5]), fmaxf(o[6], o[7])));
            #pragma unroll
            for (int off = 8; off >= 1; off >>= 1)
                rm = fmaxf(rm, __shfl_xor(rm, off, 64));
            float rs = 0.0f;
            #pragma unroll
            for (int ci = 0; ci < 8; ++ci) rs += __expf(o[ci] - rm);
            #pragma unroll
            for (int off = 8; off >= 1; off >>= 1)
                rs += __shfl_xor(rs, off, 64);
            if (tx == 0) {
                size_t pidx = ((size_t)b * LL + qq) * NKB + blockIdx.x;
                pm[pidx] = rm;
                pl[pidx] = rs;
            }
        }
    }
}

// ---------------------------------------------------------------------------
// K2: combine 16 per-block partials per row -> stats[row] = (m, 1/l)
// ---------------------------------------------------------------------------
__global__ __launch_bounds__(256) void k_reduce(
    const float* __restrict__ pm, const float* __restrict__ pl,
    float2* __restrict__ stats)
{
    int row = blockIdx.x * 256 + threadIdx.x;
    const float4* m4 = (const float4*)(pm + (size_t)row * NKB);
    const float4* l4 = (const float4*)(pl + (size_t)row * NKB);
    float4 m0 = m4[0], m1 = m4[1], m2 = m4[2], m3 = m4[3];
    float4 l0 = l4[0], l1 = l4[1], l2 = l4[2], l3 = l4[3];
    float m = fmaxf(fmaxf(fmaxf(fmaxf(m0.x, m0.y), fmaxf(m0.z, m0.w)),
                          fmaxf(fmaxf(m1.x, m1.y), fmaxf(m1.z, m1.w))),
                    fmaxf(fmaxf(fmaxf(m2.x, m2.y), fmaxf(m2.z, m2.w)),
                          fmaxf(fmaxf(m3.x, m3.y), fmaxf(m3.z, m3.w))));
    float l = l0.x * __expf(m0.x - m) + l0.y * __expf(m0.y - m)
            + l0.z * __expf(m0.z - m) + l0.w * __expf(m0.w - m)
            + l1.x * __expf(m1.x - m) + l1.y * __expf(m1.y - m)
            + l1.z * __expf(m1.z - m) + l1.w * __expf(m1.w - m)
            + l2.x * __expf(m2.x - m) + l2.y * __expf(m2.y - m)
            + l2.z * __expf(m2.z - m) + l2.w * __expf(m2.w - m)
            + l3.x * __expf(m3.x - m) + l3.y * __expf(m3.y - m)
            + l3.z * __expf(m3.z - m) + l3.w * __expf(m3.w - m);
    stats[row] = make_float2(m, 1.0f / l);
}

// ---------------------------------------------------------------------------
// K2b (fallback, tiny ws): per-row stats directly from S
// ---------------------------------------------------------------------------
__global__ __launch_bounds__(256) void k_rowstats(
    const float* __restrict__ attn, float2* __restrict__ stats)
{
    __shared__ float redm[4];
    __shared__ float reds[4];
    const float* p = attn + (size_t)blockIdx.x * LL;
    const int t = threadIdx.x;
    const int wave = t >> 6, lane = t & 63;

    float4 x0 = ((const float4*)p)[t];
    float4 x1 = ((const float4*)p)[t + 256];

    float m = fmaxf(fmaxf(fmaxf(x0.x, x0.y), fmaxf(x0.z, x0.w)),
                    fmaxf(fmaxf(x1.x, x1.y), fmaxf(x1.z, x1.w)));
    #pragma unroll
    for (int off = 32; off >= 1; off >>= 1)
        m = fmaxf(m, __shfl_xor(m, off, 64));
    if (lane == 0) redm[wave] = m;
    __syncthreads();
    m = fmaxf(fmaxf(redm[0], redm[1]), fmaxf(redm[2], redm[3]));

    float s = __expf(x0.x - m) + __expf(x0.y - m)
            + __expf(x0.z - m) + __expf(x0.w - m)
            + __expf(x1.x - m) + __expf(x1.y - m)
            + __expf(x1.z - m) + __expf(x1.w - m);
    #pragma unroll
    for (int off = 32; off >= 1; off >>= 1)
        s += __shfl_xor(s, off, 64);
    if (lane == 0) reds[wave] = s;
    __syncthreads();
    s = (reds[0] + reds[1]) + (reds[2] + reds[3]);

    if (t == 0) stats[blockIdx.x] = make_float2(m, 1.0f / s);
}

// ---------------------------------------------------------------------------
// Tier-C fallback: original in-place row softmax
// ---------------------------------------------------------------------------
__global__ __launch_bounds__(256) void k_softmax(float* __restrict__ attn)
{
    __shared__ float redm[4];
    __shared__ float reds[4];
    float* p = attn + (size_t)blockIdx.x * LL;
    const int t = threadIdx.x;
    const int wave = t >> 6, lane = t & 63;

    float4 x0 = ((const float4*)p)[t];
    float4 x1 = ((const float4*)p)[t + 256];

    float m = fmaxf(fmaxf(fmaxf(x0.x, x0.y), fmaxf(x0.z, x0.w)),
                    fmaxf(fmaxf(x1.x, x1.y), fmaxf(x1.z, x1.w)));
    #pragma unroll
    for (int off = 32; off >= 1; off >>= 1)
        m = fmaxf(m, __shfl_xor(m, off, 64));
    if (lane == 0) redm[wave] = m;
    __syncthreads();
    m = fmaxf(fmaxf(redm[0], redm[1]), fmaxf(redm[2], redm[3]));

    x0.x = expf(x0.x - m); x0.y = expf(x0.y - m);
    x0.z = expf(x0.z - m); x0.w = expf(x0.w - m);
    x1.x = expf(x1.x - m); x1.y = expf(x1.y - m);
    x1.z = expf(x1.z - m); x1.w = expf(x1.w - m);

    float s = (x0.x + x0.y + x0.z + x0.w) + (x1.x + x1.y + x1.z + x1.w);
    #pragma unroll
    for (int off = 32; off >= 1; off >>= 1)
        s += __shfl_xor(s, off, 64);
    if (lane == 0) reds[wave] = s;
    __syncthreads();
    s = (reds[0] + reds[1]) + (reds[2] + reds[3]);

    float inv = 1.0f / s;
    x0.x *= inv; x0.y *= inv; x0.z *= inv; x0.w *= inv;
    x1.x *= inv; x1.y *= inv; x1.z *= inv; x1.w *= inv;
    ((float4*)p)[t]       = x0;
    ((float4*)p)[t + 256] = x1;
}

// ---------------------------------------------------------------------------
// K3: fused softmax-apply + P write-back + PV, latency-hiding version.
// tile 64(q) x 64(d), k-chunk 64, 256 threads, 4x4 micro.
// LDS ~48.5 KB -> 3 blocks/CU; grid 1024 blocks (4/CU).
// Register double-buffer (T14): per chunk,
//   ds_write(cur) -> barrier -> [prefetch next chunk + P store-back] ->
//   compute(cur) -> barrier
// so HBM latency and store drain hide under the 2048-cycle FMA phase.
// sPT rotation swizzle col' = row + 4*(k>>2), stride 124: 2-way everywhere.
// ---------------------------------------------------------------------------
template <bool HAVE_STATS>
__global__ __launch_bounds__(256, 3) void k_pv_softmax(
    float* __restrict__ attn, const float* __restrict__ v,
    const float2* __restrict__ stats, float* __restrict__ out)
{
    __shared__ __align__(16) float sPT[64][124];  // [k][col'], col' <= 123
    __shared__ __align__(16) float sV[64][68];    // [k][d]
    __shared__ float sM[64];
    __shared__ float sIL[64];

    const int b  = blockIdx.y;
    const int q0 = blockIdx.x * 64;
    const int t  = threadIdx.x;
    const int tx = t & 15;        // d cols 4*tx .. 4*tx+3 ; also k-group / d-group in staging
    const int ty = t >> 4;        // q rows 4*ty .. 4*ty+3 ; also row base in staging

    float* pb = attn + ((size_t)b * LL + q0) * LL;
    const float* vb = v + (size_t)b * LL * DD;

    if (HAVE_STATS) {
        if (t < 64) {
            float2 st = stats[(size_t)b * LL + q0 + t];
            sM[t]  = st.x;
            sIL[t] = st.y;
        }
        __syncthreads();
    }

    // per-thread staging rows are ty+16*i, fixed float4-column tx
    float mrow[4], ilrow[4];
    if (HAVE_STATS) {
        #pragma unroll
        for (int i = 0; i < 4; ++i) {
            mrow[i]  = sM[ty + 16 * i];
            ilrow[i] = sIL[ty + 16 * i];
        }
    }

    float acc[4][4];
    #pragma unroll
    for (int i = 0; i < 4; ++i)
        #pragma unroll
        for (int j = 0; j < 4; ++j) acc[i][j] = 0.0f;

    // prefetch chunk 0 into registers
    float4 rp[4], rv[4];
    #pragma unroll
    for (int i = 0; i < 4; ++i) {
        rp[i] = *(const float4*)(pb + (size_t)(ty + 16 * i) * LL + 4 * tx);
        rv[i] = *(const float4*)(vb + (size_t)(ty + 16 * i) * DD + 4 * tx);
    }

    for (int c = 0; c < 32; ++c) {
        const int k0 = c * 64;

        // ---- write phase: expf + LDS scatter (keep P values for store-back)
        float4 pw[4];
        #pragma unroll
        for (int i = 0; i < 4; ++i) {
            int row = ty + 16 * i;
            float4 a = rp[i];
            if (HAVE_STATS) {
                float m  = mrow[i];
                float il = ilrow[i];
                a.x = __expf(a.x - m) * il;
                a.y = __expf(a.y - m) * il;
                a.z = __expf(a.z - m) * il;
                a.w = __expf(a.w - m) * il;
            }
            pw[i] = a;
            int cc = row + 4 * tx;            // rotation swizzle
            sPT[4 * tx + 0][cc] = a.x;
            sPT[4 * tx + 1][cc] = a.y;
            sPT[4 * tx + 2][cc] = a.z;
            sPT[4 * tx + 3][cc] = a.w;
            *(float4*)&sV[row][4 * tx] = rv[i];
        }
        __syncthreads();

        // ---- prefetch next chunk + P write-back; both drain under compute
        if (c < 31) {
            const int k1 = k0 + 64;
            #pragma unroll
            for (int i = 0; i < 4; ++i) {
                rp[i] = *(const float4*)(pb + (size_t)(ty + 16 * i) * LL + k1 + 4 * tx);
                rv[i] = *(const float4*)(vb + (size_t)(k1 + ty + 16 * i) * DD + 4 * tx);
            }
        }
        if (HAVE_STATS) {
            #pragma unroll
            for (int i = 0; i < 4; ++i)
                *(float4*)(pb + (size_t)(ty + 16 * i) * LL + k0 + 4 * tx) = pw[i];
        }

        // ---- compute: acc += P_chunk^T-slice * V_chunk
        #pragma unroll
        for (int kg = 0; kg < 16; ++kg) {
            const int rot = 4 * kg;
            #pragma unroll
            for (int c2 = 0; c2 < 4; ++c2) {
                const int kk = 4 * kg + c2;
                float4 a0 = *(const float4*)&sPT[kk][4 * ty + rot];
                float4 b0 = *(const float4*)&sV[kk][4 * tx];
                float aa[4] = {a0.x, a0.y, a0.z, a0.w};
                float bb[4] = {b0.x, b0.y, b0.z, b0.w};
                #pragma unroll
                for (int ri = 0; ri < 4; ++ri)
                    #pragma unroll
                    for (int ci = 0; ci < 4; ++ci)
                        acc[ri][ci] = fmaf(aa[ri], bb[ci], acc[ri][ci]);
            }
        }
        __syncthreads();
    }

    #pragma unroll
    for (int ri = 0; ri < 4; ++ri) {
        float4 o = make_float4(acc[ri][0], acc[ri][1], acc[ri][2], acc[ri][3]);
        *(float4*)(out + ((size_t)b * LL + q0 + 4 * ty + ri) * DD + 4 * tx) = o;
    }
}

// ---------------------------------------------------------------------------
extern "C" void kernel_launch(void* const* d_in, const int* in_sizes, int n_in,
                              void* d_out, int out_size, void* d_ws, size_t ws_size,
                              hipStream_t stream)
{
    const float* q    = (const float*)d_in[0];
    const float* k    = (const float*)d_in[1];
    const float* v    = (const float*)d_in[2];
    const int*   diag = (const int*)d_in[3];
    const int*   mask = (const int*)d_in[4];   // ASSUMPTION: bool uploaded as int32

    float* out  = (float*)d_out;                       // [B, L, D]
    float* attn = out + (size_t)BB * LL * DD;          // [B, L, L]

    const size_t ROWS = (size_t)BB * LL;               // 65536
    const size_t PART_FLOATS = ROWS * NKB;
    const size_t needA = PART_FLOATS * 4 * 2 + ROWS * 8;   // pm+pl+stats ~8.5 MB
    const size_t needB = ROWS * 8;                          // stats only  512 KB

    if (d_ws != nullptr && ws_size >= needA) {
        // Tier A: fused-stats pipeline
        float*  pm    = (float*)d_ws;
        float*  pl    = pm + PART_FLOATS;
        float2* stats = (float2*)(pl + PART_FLOATS);
        k_scores<<<dim3(LL / 128, LL / 128, BB), 256, 0, stream>>>(
            q, k, diag, mask, attn, pm, pl);
        k_reduce<<<dim3((int)(ROWS / 256)), 256, 0, stream>>>(pm, pl, stats);
        k_pv_softmax<true><<<dim3(LL / 64, BB), 256, 0, stream>>>(attn, v, stats, out);
    } else if (d_ws != nullptr && ws_size >= needB) {
        // Tier B: stats recomputed from S
        float2* stats = (float2*)d_ws;
        k_scores<<<dim3(LL / 128, LL / 128, BB), 256, 0, stream>>>(
            q, k, diag, mask, attn, nullptr, nullptr);
        k_rowstats<<<dim3(BB * LL), 256, 0, stream>>>(attn, stats);
        k_pv_softmax<true><<<dim3(LL / 64, BB), 256, 0, stream>>>(attn, v, stats, out);
    } else {
        // Tier C: 3-pass pipeline, no workspace
        k_scores<<<dim3(LL / 128, LL / 128, BB), 256, 0, stream>>>(
            q, k, diag, mask, attn, nullptr, nullptr);
        k_softmax<<<dim3(BB * LL), 256, 0, stream>>>(attn);
        k_pv_softmax<false><<<dim3(LL / 64, BB), 256, 0, stream>>>(attn, v, nullptr, out);
    }
}

// Round 4
// 1657.816 us; speedup vs baseline: 1.2145x; 1.2145x over previous
//
#include <hip/hip_runtime.h>
#include <cstdint>
#include <cstddef>

#define BB 32
#define LL 2048
#define DD 64

// masked scores get a huge negative finite value: expf(s - m) == 0 exactly,
// identical post-softmax to the reference's -inf / -1e32 fills.
#define BIG_NEG (-3.0e38f)

// ---------------------------------------------------------------------------
// K1: raw masked scores  S[b][q][k] = (q·k)/8, masked -> BIG_NEG
// tile 128(q) x 128(k), 256 threads, 8x8 micro, D chunked by 32 in LDS.
// LDS layout: transposed [d][col'] with rotation swizzle col' = col + 4*(d>>2)
//   col stride 156 (156 % 32 == 28): staging scatter writes and all fragment
//   reads are exactly 2-way bank-aliased (free on CDNA4) -- measured
//   SQ_LDS_BANK_CONFLICT 9.2e7 -> 0 in round 2.
// Everything else identical to the round-0 kernel (VGPR 64, no spills).
// ---------------------------------------------------------------------------
__global__ __launch_bounds__(256) void k_scores(
    const float* __restrict__ q, const float* __restrict__ kmat,
    const int* __restrict__ diag, const int* __restrict__ mask,
    float* __restrict__ attn)
{
    __shared__ __align__(16) float sQT[32][156];  // [d][col'], col' <= 155
    __shared__ __align__(16) float sKT[32][156];

    const int b  = blockIdx.z;
    const int q0 = blockIdx.y * 128;
    const int k0 = blockIdx.x * 128;
    const int t  = threadIdx.x;
    const int tx = t & 15;        // col group: cols 8*tx .. 8*tx+7 (as 4+4)
    const int ty = t >> 4;        // row group: rows 8*ty .. 8*ty+7
    const int tyb = ty * 8;
    const int txb = tx * 4;

    const float* qb = q    + ((size_t)b * LL + q0) * DD;
    const float* kb = kmat + ((size_t)b * LL + k0) * DD;

    float acc[8][8];
    #pragma unroll
    for (int i = 0; i < 8; ++i)
        #pragma unroll
        for (int j = 0; j < 8; ++j) acc[i][j] = 0.0f;

    for (int dc = 0; dc < DD; dc += 32) {
        // stage 128 rows x 32 d of Q and K, transposed + rotation-swizzled
        #pragma unroll
        for (int i = 0; i < 4; ++i) {
            int lin = t + 256 * i;        // 0..1023 float4 slots
            int row = lin >> 3;           // 0..127
            int dv  = lin & 7;            // d4 block 0..7
            int cc  = row + dv * 4;       // rotation swizzle, <= 155
            float4 a = *(const float4*)(qb + (size_t)row * DD + dc + dv * 4);
            sQT[dv * 4 + 0][cc] = a.x;
            sQT[dv * 4 + 1][cc] = a.y;
            sQT[dv * 4 + 2][cc] = a.z;
            sQT[dv * 4 + 3][cc] = a.w;
            float4 c4 = *(const float4*)(kb + (size_t)row * DD + dc + dv * 4);
            sKT[dv * 4 + 0][cc] = c4.x;
            sKT[dv * 4 + 1][cc] = c4.y;
            sKT[dv * 4 + 2][cc] = c4.z;
            sKT[dv * 4 + 3][cc] = c4.w;
        }
        __syncthreads();

        // compute: rotation offset is compile-time constant per d-group
        #pragma unroll
        for (int dg = 0; dg < 8; ++dg) {
            const int rot = dg * 4;
            #pragma unroll
            for (int dc2 = 0; dc2 < 4; ++dc2) {
                const int d = dg * 4 + dc2;
                float4 a0 = *(const float4*)&sQT[d][tyb + rot];
                float4 a1 = *(const float4*)&sQT[d][tyb + 4 + rot];
                float4 b0 = *(const float4*)&sKT[d][txb + rot];
                float4 b1 = *(const float4*)&sKT[d][txb + 64 + rot];
                float aa[8] = {a0.x, a0.y, a0.z, a0.w, a1.x, a1.y, a1.z, a1.w};
                float bb[8] = {b0.x, b0.y, b0.z, b0.w, b1.x, b1.y, b1.z, b1.w};
                #pragma unroll
                for (int ri = 0; ri < 8; ++ri)
                    #pragma unroll
                    for (int ci = 0; ci < 8; ++ci)
                        acc[ri][ci] = fmaf(aa[ri], bb[ci], acc[ri][ci]);
            }
        }
        __syncthreads();
    }

    // epilogue: scale by 1/8, apply masks, write raw scores (round-0 form:
    // use-adjacent mask loads, no register pipeline -> no spills)
    #pragma unroll
    for (int ri = 0; ri < 8; ++ri) {
        int qq = q0 + tyb + ri;
        size_t base = ((size_t)b * LL + qq) * LL + (size_t)(k0 + txb);
        int4 dm0 = *(const int4*)(diag + base);
        int4 dm1 = *(const int4*)(diag + base + 64);
        int4 mk0 = *(const int4*)(mask + base);
        int4 mk1 = *(const int4*)(mask + base + 64);
        int dmv[8] = {dm0.x, dm0.y, dm0.z, dm0.w, dm1.x, dm1.y, dm1.z, dm1.w};
        int mkv[8] = {mk0.x, mk0.y, mk0.z, mk0.w, mk1.x, mk1.y, mk1.z, mk1.w};
        float o[8];
        #pragma unroll
        for (int ci = 0; ci < 8; ++ci) {
            float s = acc[ri][ci] * 0.125f;
            o[ci] = (dmv[ci] == 0 || mkv[ci] != 0) ? BIG_NEG : s;
        }
        *(float4*)(attn + base)      = make_float4(o[0], o[1], o[2], o[3]);
        *(float4*)(attn + base + 64) = make_float4(o[4], o[5], o[6], o[7]);
    }
}

// ---------------------------------------------------------------------------
// K2: in-place row softmax over L=2048. One block per (b,q) row.
// Row lives in registers: 256 threads x 8 floats. (round-0 form, __expf)
// ---------------------------------------------------------------------------
__global__ __launch_bounds__(256) void k_softmax(float* __restrict__ attn)
{
    __shared__ float redm[4];
    __shared__ float reds[4];
    float* p = attn + (size_t)blockIdx.x * LL;
    const int t = threadIdx.x;
    const int wave = t >> 6, lane = t & 63;

    float4 x0 = ((const float4*)p)[t];         // elems 4t..4t+3
    float4 x1 = ((const float4*)p)[t + 256];   // elems 1024+4t..

    float m = fmaxf(fmaxf(fmaxf(x0.x, x0.y), fmaxf(x0.z, x0.w)),
                    fmaxf(fmaxf(x1.x, x1.y), fmaxf(x1.z, x1.w)));
    #pragma unroll
    for (int off = 32; off >= 1; off >>= 1)
        m = fmaxf(m, __shfl_xor(m, off, 64));
    if (lane == 0) redm[wave] = m;
    __syncthreads();
    m = fmaxf(fmaxf(redm[0], redm[1]), fmaxf(redm[2], redm[3]));

    x0.x = __expf(x0.x - m); x0.y = __expf(x0.y - m);
    x0.z = __expf(x0.z - m); x0.w = __expf(x0.w - m);
    x1.x = __expf(x1.x - m); x1.y = __expf(x1.y - m);
    x1.z = __expf(x1.z - m); x1.w = __expf(x1.w - m);

    float s = (x0.x + x0.y + x0.z + x0.w) + (x1.x + x1.y + x1.z + x1.w);
    #pragma unroll
    for (int off = 32; off >= 1; off >>= 1)
        s += __shfl_xor(s, off, 64);
    if (lane == 0) reds[wave] = s;
    __syncthreads();
    s = (reds[0] + reds[1]) + (reds[2] + reds[3]);

    float inv = 1.0f / s;
    x0.x *= inv; x0.y *= inv; x0.z *= inv; x0.w *= inv;
    x1.x *= inv; x1.y *= inv; x1.z *= inv; x1.w *= inv;
    ((float4*)p)[t]       = x0;
    ((float4*)p)[t + 256] = x1;
}

// ---------------------------------------------------------------------------
// K3: out[b][q][d] = sum_k P[b][q][k] * V[b][k][d]
// tile 128(q) x 64(d=full D), TK=64, 256 threads, 8x4 micro. (round-0 exact)
// ---------------------------------------------------------------------------
__global__ __launch_bounds__(256) void k_pv(
    const float* __restrict__ attn, const float* __restrict__ v,
    float* __restrict__ out)
{
    __shared__ __align__(16) float sPT[64][132];  // [k][row]
    __shared__ __align__(16) float sV[64][68];    // [k][d]

    const int b  = blockIdx.y;
    const int q0 = blockIdx.x * 128;
    const int t  = threadIdx.x;
    const int tx = t & 15;        // cols 4*tx .. 4*tx+3
    const int ty = t >> 4;        // rows 8*ty .. 8*ty+7

    const float* pb = attn + ((size_t)b * LL + q0) * LL;
    const float* vb = v + (size_t)b * LL * DD;

    float acc[8][4];
    #pragma unroll
    for (int i = 0; i < 8; ++i)
        #pragma unroll
        for (int j = 0; j < 4; ++j) acc[i][j] = 0.0f;

    for (int k0 = 0; k0 < LL; k0 += 64) {
        // stage P tile 128 x 64, transposed
        #pragma unroll
        for (int i = 0; i < 8; ++i) {
            int lin = t + 256 * i;   // 0..2047 float4 slots
            int row = lin >> 4;      // 0..127
            int kv  = lin & 15;
            float4 a = *(const float4*)(pb + (size_t)row * LL + k0 + kv * 4);
            sPT[kv * 4 + 0][row] = a.x;
            sPT[kv * 4 + 1][row] = a.y;
            sPT[kv * 4 + 2][row] = a.z;
            sPT[kv * 4 + 3][row] = a.w;
        }
        // stage V tile 64 x 64, natural
        #pragma unroll
        for (int i = 0; i < 4; ++i) {
            int lin = t + 256 * i;   // 0..1023
            int row = lin >> 4;      // 0..63
            int dv  = lin & 15;
            *(float4*)&sV[row][dv * 4] =
                *(const float4*)(vb + (size_t)(k0 + row) * DD + dv * 4);
        }
        __syncthreads();

        #pragma unroll 8
        for (int kk = 0; kk < 64; ++kk) {
            float4 a0 = *(const float4*)&sPT[kk][ty * 8];
            float4 a1 = *(const float4*)&sPT[kk][ty * 8 + 4];
            float4 b0 = *(const float4*)&sV[kk][tx * 4];
            float aa[8] = {a0.x, a0.y, a0.z, a0.w, a1.x, a1.y, a1.z, a1.w};
            float bb[4] = {b0.x, b0.y, b0.z, b0.w};
            #pragma unroll
            for (int ri = 0; ri < 8; ++ri)
                #pragma unroll
                for (int ci = 0; ci < 4; ++ci)
                    acc[ri][ci] = fmaf(aa[ri], bb[ci], acc[ri][ci]);
        }
        __syncthreads();
    }

    #pragma unroll
    for (int ri = 0; ri < 8; ++ri) {
        float4 o = make_float4(acc[ri][0], acc[ri][1], acc[ri][2], acc[ri][3]);
        *(float4*)(out + ((size_t)b * LL + q0 + ty * 8 + ri) * DD + tx * 4) = o;
    }
}

// ---------------------------------------------------------------------------
extern "C" void kernel_launch(void* const* d_in, const int* in_sizes, int n_in,
                              void* d_out, int out_size, void* d_ws, size_t ws_size,
                              hipStream_t stream)
{
    const float* q    = (const float*)d_in[0];
    const float* k    = (const float*)d_in[1];
    const float* v    = (const float*)d_in[2];
    const int*   diag = (const int*)d_in[3];
    const int*   mask = (const int*)d_in[4];   // ASSUMPTION: bool uploaded as int32

    float* out  = (float*)d_out;                       // [B, L, D]
    float* attn = out + (size_t)BB * LL * DD;          // [B, L, L]

    k_scores <<<dim3(LL / 128, LL / 128, BB), 256, 0, stream>>>(q, k, diag, mask, attn);
    k_softmax<<<dim3(BB * LL),                256, 0, stream>>>(attn);
    k_pv     <<<dim3(LL / 128, BB),           256, 0, stream>>>(attn, v, out);
}